// Round 2
// baseline (734.953 us; speedup 1.0000x reference)
//
#include <hip/hip_runtime.h>
#include <math.h>

#define D_IN  512
#define D_HID 16
#define D_OUT 64

// ---------------------------------------------------------------------------
__global__ void k_zero_deg(int* __restrict__ deg, int n) {
    int i = blockIdx.x * blockDim.x + threadIdx.x;
    if (i < n) deg[i] = 0;
}

__global__ void k_deg(const int* __restrict__ dst, int* __restrict__ deg, int E) {
    int e = blockIdx.x * blockDim.x + threadIdx.x;
    if (e < E) atomicAdd(&deg[dst[e]], 1);
}

// block b sums deg over its 1024-element chunk -> partial[b]
__global__ __launch_bounds__(256) void k_scan1(const int* __restrict__ deg,
                                               int* __restrict__ partial, int n) {
    __shared__ int s[256];
    int t = threadIdx.x;
    int base = blockIdx.x * 1024 + t * 4;
    int sum = 0;
#pragma unroll
    for (int k = 0; k < 4; k++) { int i = base + k; if (i < n) sum += deg[i]; }
    s[t] = sum; __syncthreads();
    for (int off = 128; off; off >>= 1) { if (t < off) s[t] += s[t + off]; __syncthreads(); }
    if (t == 0) partial[blockIdx.x] = s[0];
}

// single block: exclusive scan of partials (nblk <= 256)
__global__ __launch_bounds__(256) void k_scan2(int* __restrict__ partial, int nblk) {
    __shared__ int s[256];
    int t = threadIdx.x;
    int v = (t < nblk) ? partial[t] : 0;
    s[t] = v; __syncthreads();
    for (int off = 1; off < 256; off <<= 1) {
        int u = (t >= off) ? s[t - off] : 0;
        __syncthreads();
        s[t] += u;
        __syncthreads();
    }
    if (t < nblk) partial[t] = s[t] - v;
}

// block b: local exclusive scan + chunk offset -> rowptr/cursor; dis = rsqrt(deg+1)
__global__ __launch_bounds__(256) void k_scan3(const int* __restrict__ deg,
                                               const int* __restrict__ partial,
                                               int* __restrict__ rowptr, int* __restrict__ cursor,
                                               float* __restrict__ dis, int n) {
    __shared__ int s[256];
    int t = threadIdx.x;
    int i0 = blockIdx.x * 1024 + t * 4;
    int d[4]; int ls = 0;
#pragma unroll
    for (int k = 0; k < 4; k++) { int i = i0 + k; d[k] = (i < n) ? deg[i] : 0; ls += d[k]; }
    s[t] = ls; __syncthreads();
    for (int off = 1; off < 256; off <<= 1) {
        int u = (t >= off) ? s[t - off] : 0;
        __syncthreads();
        s[t] += u;
        __syncthreads();
    }
    int run = partial[blockIdx.x] + s[t] - ls;
#pragma unroll
    for (int k = 0; k < 4; k++) {
        int i = i0 + k;
        if (i < n) {
            rowptr[i] = run;
            cursor[i] = run;
            dis[i] = rsqrtf((float)(d[k] + 1));
            run += d[k];
            if (i == n - 1) rowptr[n] = run;
        }
    }
}

__global__ void k_fill(const int* __restrict__ src, const int* __restrict__ dst,
                       int* __restrict__ cursor, int* __restrict__ csr_src, int E) {
    int e = blockIdx.x * blockDim.x + threadIdx.x;
    if (e < E) {
        int slot = atomicAdd(&cursor[dst[e]], 1);
        csr_src[slot] = src[e];
    }
}

// m1[r][j] = dis[r] * sum_k x[r][k] * W1[k][j]; 4 threads per row.
__global__ __launch_bounds__(256) void k_gemm1(const float* __restrict__ x,
                                               const float* __restrict__ W1,
                                               const float* __restrict__ dis,
                                               float* __restrict__ m1, int n) {
    __shared__ float w[D_IN * D_HID];  // 32 KiB
    for (int i = threadIdx.x; i < (D_IN * D_HID) / 4; i += 256)
        ((float4*)w)[i] = ((const float4*)W1)[i];
    __syncthreads();

    int gid  = blockIdx.x * blockDim.x + threadIdx.x;
    int row  = gid >> 2;
    int part = gid & 3;
    if (row >= n) return;

    const float4* xr = (const float4*)(x + (size_t)row * D_IN + part * 128);
    float acc[D_HID];
#pragma unroll
    for (int j = 0; j < D_HID; j++) acc[j] = 0.0f;

#pragma unroll 4
    for (int m = 0; m < 32; m++) {
        float4 xv = xr[m];
        int kb = part * 128 + m * 4;
        const float* w0 = &w[(kb + 0) * D_HID];
        const float* w1 = &w[(kb + 1) * D_HID];
        const float* w2 = &w[(kb + 2) * D_HID];
        const float* w3 = &w[(kb + 3) * D_HID];
#pragma unroll
        for (int j = 0; j < D_HID; j++)
            acc[j] += xv.x * w0[j] + xv.y * w1[j] + xv.z * w2[j] + xv.w * w3[j];
    }
#pragma unroll
    for (int j = 0; j < D_HID; j++) {
        acc[j] += __shfl_xor(acc[j], 1);
        acc[j] += __shfl_xor(acc[j], 2);
    }
    float s = dis[row];
    float4 o;
    o.x = s * acc[part * 4 + 0];
    o.y = s * acc[part * 4 + 1];
    o.z = s * acc[part * 4 + 2];
    o.w = s * acc[part * 4 + 3];
    ((float4*)(m1 + (size_t)row * D_HID))[part] = o;
}

// gather layer 1: out[d][j] = dis[d]*relu(dis[d]*(sum_src m1[src][j] + m1[d][j]) + b1[j])
__global__ __launch_bounds__(256) void k_gather1(const int* __restrict__ rowptr,
                                                 const int* __restrict__ csr_src,
                                                 const float* __restrict__ m1,
                                                 const float* __restrict__ dis,
                                                 const float* __restrict__ b1,
                                                 float* __restrict__ outb, int n) {
    int tid = blockIdx.x * blockDim.x + threadIdx.x;
    int node = tid >> 4, j = tid & 15;
    if (node >= n) return;
    int s0 = rowptr[node], s1 = rowptr[node + 1];
    float acc = m1[(size_t)node * D_HID + j];  // self-loop
    for (int e = s0; e < s1; e++)
        acc += m1[(size_t)csr_src[e] * D_HID + j];
    float di = dis[node];
    float z = fmaxf(di * acc + b1[j], 0.0f);
    outb[(size_t)node * D_HID + j] = di * z;
}

// gather layer 2: g[d][j] = dis[d]*(sum_src m[src][j] + m[d][j])
__global__ __launch_bounds__(256) void k_gather2(const int* __restrict__ rowptr,
                                                 const int* __restrict__ csr_src,
                                                 const float* __restrict__ m,
                                                 const float* __restrict__ dis,
                                                 float* __restrict__ g, int n) {
    int tid = blockIdx.x * blockDim.x + threadIdx.x;
    int node = tid >> 4, j = tid & 15;
    if (node >= n) return;
    int s0 = rowptr[node], s1 = rowptr[node + 1];
    float acc = m[(size_t)node * D_HID + j];
    for (int e = s0; e < s1; e++)
        acc += m[(size_t)csr_src[e] * D_HID + j];
    g[(size_t)node * D_HID + j] = dis[node] * acc;
}

// out_row = g @ W2 + b2, then log_softmax over 64 lanes (one wave per node)
__global__ __launch_bounds__(256) void k_final(const float* __restrict__ g,
                                               const float* __restrict__ W2,
                                               const float* __restrict__ b2,
                                               float* __restrict__ out, int n) {
    int lane = threadIdx.x & 63;
    int node = blockIdx.x * 4 + (threadIdx.x >> 6);
    if (node >= n) return;

    float gv[D_HID];
    const float4* g4 = (const float4*)(g + (size_t)node * D_HID);
#pragma unroll
    for (int q = 0; q < 4; q++) {
        float4 v4 = g4[q];
        gv[q * 4 + 0] = v4.x; gv[q * 4 + 1] = v4.y;
        gv[q * 4 + 2] = v4.z; gv[q * 4 + 3] = v4.w;
    }
    float v = b2[lane];
#pragma unroll
    for (int j = 0; j < D_HID; j++) v += gv[j] * W2[j * D_OUT + lane];

    float mx = v;
#pragma unroll
    for (int off = 32; off; off >>= 1) mx = fmaxf(mx, __shfl_xor(mx, off));
    float ev = expf(v - mx);
    float sum = ev;
#pragma unroll
    for (int off = 32; off; off >>= 1) sum += __shfl_xor(sum, off);
    out[(size_t)node * D_OUT + lane] = (v - mx) - logf(sum);
}

// ---------------------------------------------------------------------------
extern "C" void kernel_launch(void* const* d_in, const int* in_sizes, int n_in,
                              void* d_out, int out_size, void* d_ws, size_t ws_size,
                              hipStream_t stream) {
    const float* x  = (const float*)d_in[0];
    const int*   ei = (const int*)d_in[1];
    const float* W1 = (const float*)d_in[2];
    const float* b1 = (const float*)d_in[3];
    const float* W2 = (const float*)d_in[4];
    const float* b2 = (const float*)d_in[5];
    float* out = (float*)d_out;

    int n = in_sizes[0] / D_IN;   // 100000
    int E = in_sizes[1] / 2;      // 3200000
    const int* src = ei;
    const int* dst = ei + E;

    int* deg     = (int*)d_ws;                 // n
    int* rowptr  = deg + n;                    // n+1
    int* cursor  = rowptr + n + 1;             // n
    int* partial = cursor + n;                 // 256
    int* csr_src = partial + 256;              // E
    float* dis   = (float*)(csr_src + E);      // n
    float* bufA  = dis + n;                    // 16n
    float* bufB  = bufA + (size_t)n * D_HID;   // 16n

    const int B = 256;
    int nblk = (n + 1023) / 1024;              // 98 (<= 256)

    k_zero_deg<<<(n + B - 1) / B, B, 0, stream>>>(deg, n);
    k_deg     <<<(E + B - 1) / B, B, 0, stream>>>(dst, deg, E);
    k_scan1   <<<nblk, B, 0, stream>>>(deg, partial, n);
    k_scan2   <<<1, B, 0, stream>>>(partial, nblk);
    k_scan3   <<<nblk, B, 0, stream>>>(deg, partial, rowptr, cursor, dis, n);
    k_fill    <<<(E + B - 1) / B, B, 0, stream>>>(src, dst, cursor, csr_src, E);
    k_gemm1   <<<(n * 4 + B - 1) / B, B, 0, stream>>>(x, W1, dis, bufA, n);
    k_gather1 <<<((size_t)n * D_HID + B - 1) / B, B, 0, stream>>>(rowptr, csr_src, bufA, dis, b1, bufB, n);
    k_gather2 <<<((size_t)n * D_HID + B - 1) / B, B, 0, stream>>>(rowptr, csr_src, bufB, dis, bufA, n);
    k_final   <<<(n + 3) / 4, B, 0, stream>>>(bufA, W2, b2, out, n);
}